// Round 1
// baseline (3049.500 us; speedup 1.0000x reference)
//
#include <hip/hip_runtime.h>
#include <math.h>

// Problem constants: N=4, S=2048, D_IN=D_OUT=1024, all fp32.
// Pipeline: wv=v@WVt, wq=q@WQt, wk=k@WKt  ->  P=wq@wkt  ->  softmax over q (axis=1), /1024  ->  out=P@wv
// All GEMM dims are multiples of 128/16, so no bounds checks.

#define BM 128
#define BN 128
#define BK 16
#define TM 8
#define TN 8
// threads = (BM/TM)*(BN/TN) = 256

template<bool TRANS_B>
__global__ __launch_bounds__(256)
void gemm_f32_kernel(const float* __restrict__ A, const float* __restrict__ B,
                     float* __restrict__ C,
                     int M, int Nc, int K,
                     long strideA, long strideB, long strideC)
{
    const int n0 = blockIdx.x * BN;
    const int m0 = blockIdx.y * BM;
    const int b  = blockIdx.z;
    A += (long)b * strideA;
    B += (long)b * strideB;
    C += (long)b * strideC;

    __shared__ float As[BK][BM + 1];   // +1 pad: kills 16-way bank conflict on transposed store
    __shared__ float Bs[BK][BN + 1];

    const int tid = threadIdx.x;   // 0..255
    const int tx  = tid & 15;      // n-direction
    const int ty  = tid >> 4;      // m-direction

    float acc[TM][TN];
#pragma unroll
    for (int i = 0; i < TM; i++)
#pragma unroll
        for (int j = 0; j < TN; j++) acc[i][j] = 0.f;

    for (int k0 = 0; k0 < K; k0 += BK) {
        // A tile: [BM rows x BK k], row-major lda=K. 2048 elems / 256 thr = 8 each.
        // consecutive tid -> consecutive k (64B runs); LDS store transposed with pad.
#pragma unroll
        for (int i = 0; i < (BM * BK) / 256; i++) {
            int idx = tid + i * 256;
            int m = idx >> 4;      // /BK
            int kk = idx & 15;     // %BK
            As[kk][m] = A[(long)(m0 + m) * K + k0 + kk];
        }
        if (TRANS_B) {
            // B is [Nc,K] row-major (C = A·Bt): Bs[k][n] = B[n0+n][k0+k]
#pragma unroll
            for (int i = 0; i < (BN * BK) / 256; i++) {
                int idx = tid + i * 256;
                int n = idx >> 4;
                int kk = idx & 15;
                Bs[kk][n] = B[(long)(n0 + n) * K + k0 + kk];
            }
        } else {
            // B is [K,Nc] row-major (C = A·B): Bs[k][n] = B[k0+k][n0+n], fully coalesced
#pragma unroll
            for (int i = 0; i < (BN * BK) / 256; i++) {
                int idx = tid + i * 256;
                int kk = idx >> 7;        // /BN
                int n  = idx & (BN - 1);  // %BN
                Bs[kk][n] = B[(long)(k0 + kk) * Nc + n0 + n];
            }
        }
        __syncthreads();

#pragma unroll
        for (int kk = 0; kk < BK; kk++) {
            float ra[TM], rb[TN];
#pragma unroll
            for (int i = 0; i < TM; i++) ra[i] = As[kk][ty * TM + i];
#pragma unroll
            for (int j = 0; j < TN; j++) rb[j] = Bs[kk][tx * TN + j];
#pragma unroll
            for (int i = 0; i < TM; i++)
#pragma unroll
                for (int j = 0; j < TN; j++)
                    acc[i][j] += ra[i] * rb[j];
        }
        __syncthreads();
    }

#pragma unroll
    for (int i = 0; i < TM; i++) {
#pragma unroll
        for (int j = 0; j < TN; j++) {
            C[(long)(m0 + ty * TM + i) * Nc + n0 + tx * TN + j] = acc[i][j];
        }
    }
}

// Softmax over the QUERY axis (axis=1) of P[N][Sq][Sk], then multiply by inv_scale.
// Block: 256 thr = 64 columns x 4 q-stripes. Grid: (Sk/64, N).
__global__ __launch_bounds__(256)
void softmax_col_kernel(float* __restrict__ P, int S, float inv_scale)
{
    const int n  = blockIdx.y;
    const int c  = threadIdx.x & 63;    // column within the block's 64
    const int qs = threadIdx.x >> 6;    // stripe 0..3
    const int kk = blockIdx.x * 64 + c;
    float* Pn = P + (long)n * S * S;

    __shared__ float red[4][64];

    // pass 1: column max (coalesced: lanes of a wave span consecutive k)
    float m = -INFINITY;
    for (int q = qs; q < S; q += 4)
        m = fmaxf(m, Pn[(long)q * S + kk]);
    red[qs][c] = m;
    __syncthreads();
    m = fmaxf(fmaxf(red[0][c], red[1][c]), fmaxf(red[2][c], red[3][c]));
    __syncthreads();

    // pass 2: exp & partial sum (store exp in place)
    float s = 0.f;
    for (int q = qs; q < S; q += 4) {
        float e = expf(Pn[(long)q * S + kk] - m);
        Pn[(long)q * S + kk] = e;
        s += e;
    }
    red[qs][c] = s;
    __syncthreads();
    s = red[0][c] + red[1][c] + red[2][c] + red[3][c];
    const float r = inv_scale / s;

    // pass 3: normalize + post-softmax /D_IN
    for (int q = qs; q < S; q += 4)
        Pn[(long)q * S + kk] *= r;
}

extern "C" void kernel_launch(void* const* d_in, const int* in_sizes, int n_in,
                              void* d_out, int out_size, void* d_ws, size_t ws_size,
                              hipStream_t stream)
{
    const float* v  = (const float*)d_in[0];
    const float* k  = (const float*)d_in[1];
    const float* q  = (const float*)d_in[2];
    const float* WV = (const float*)d_in[3];
    const float* WQ = (const float*)d_in[4];
    const float* WK = (const float*)d_in[5];
    float* out = (float*)d_out;

    const int N = 4, S = 2048, D = 1024;

    // workspace layout (floats): wv | wq | wk | P   = 3*8.4M + 16.8M = 41.9M floats (168 MB)
    float* wv = (float*)d_ws;
    float* wq = wv + (size_t)N * S * D;
    float* wk = wq + (size_t)N * S * D;
    float* P  = wk + (size_t)N * S * D;

    dim3 blk(256);

    // projections: fold batch into M = N*S = 8192 rows; C = X @ W^T  (NT)
    {
        dim3 g(D / BN, (N * S) / BM, 1);
        gemm_f32_kernel<true><<<g, blk, 0, stream>>>(v, WV, wv, N * S, D, D, 0, 0, 0);
        gemm_f32_kernel<true><<<g, blk, 0, stream>>>(q, WQ, wq, N * S, D, D, 0, 0, 0);
        gemm_f32_kernel<true><<<g, blk, 0, stream>>>(k, WK, wk, N * S, D, D, 0, 0, 0);
    }
    // scores: P[n] = wq[n] @ wk[n]^T   (NT, batched via grid.z)
    {
        dim3 g(S / BN, S / BM, N);
        gemm_f32_kernel<true><<<g, blk, 0, stream>>>(wq, wk, P, S, S, D,
                                                     (long)S * D, (long)S * D, (long)S * S);
    }
    // softmax over q (axis=1), then /D_IN
    {
        dim3 g(S / 64, N);
        softmax_col_kernel<<<g, blk, 0, stream>>>(P, S, 1.0f / (float)D);
    }
    // out[n] = P[n] @ wv[n]   (NN, batched)
    {
        dim3 g(D / BN, S / BM, N);
        gemm_f32_kernel<false><<<g, blk, 0, stream>>>(P, wv, out, S, D, S,
                                                      (long)S * S, (long)S * D, (long)S * D);
    }
}

// Round 2
// 906.449 us; speedup vs baseline: 3.3642x; 3.3642x over previous
//
#include <hip/hip_runtime.h>
#include <math.h>

// N=4, S=2048, D=1024, fp32 in/out.
// Pipeline (all GEMMs = f16 MFMA with 2-way fp16 split, 3 cross-products hh+hl+lh):
//   wq = q@WQt, wk = k@WKt (split-plane out), wvT = (v@WVt)^T (split-plane out, transposed)
//   Sc = wq@wkt (split-plane out, scaled 1/16)  ->  column softmax (axis=q) /1024 -> P planes
//   out = P@wvT^T (fp32 out)
// Workspace (f16 elems), exactly 167.8 MB:
//   R1 [0 .. 4*NSD): wq_hi|wq_lo|wk_hi|wk_lo ; reused after softmax as P_hi|P_lo (2*NSS == 4*NSD)
//   R2 [4*NSD .. 8*NSD): Sc_hi|Sc_lo
//   R3 [8*NSD .. 10*NSD): wvT_hi|wvT_lo

typedef _Float16 f16;
typedef _Float16 f16x8 __attribute__((ext_vector_type(8)));
typedef float f32x4 __attribute__((ext_vector_type(4)));

enum StageMode { STAGE_F32SPLIT, STAGE_PLANES };
enum EpiMode   { EPI_F32, EPI_SPLIT, EPI_SPLIT_T };

// LDS tile: 128 rows x 32 k (f16), row pitch 40 f16 (80 B = 5 x 16B chunks;
// 5 coprime 8 bank-quads -> conflict-free ds_read_b128 across 16 rows).
#define LDS_PITCH 40

template<StageMode SM>
__device__ __forceinline__ void stage_tile(const void* __restrict__ Phi,
                                           const void* __restrict__ Plo,
                                           f16* __restrict__ Shi, f16* __restrict__ Slo,
                                           long rowBase, int ld, int k0, int tid)
{
    if constexpr (SM == STAGE_PLANES) {
        const f16* gh = (const f16*)Phi;
        const f16* gl = (const f16*)Plo;
#pragma unroll
        for (int i = 0; i < 2; i++) {
            int c  = tid + i * 256;      // 512 chunks of 8 f16
            int r  = c >> 2;             // row 0..127
            int cc = c & 3;              // 16B chunk within row
            long g = (rowBase + r) * (long)ld + k0 + cc * 8;
            *(uint4*)&Shi[r * LDS_PITCH + cc * 8] = *(const uint4*)&gh[g];
            *(uint4*)&Slo[r * LDS_PITCH + cc * 8] = *(const uint4*)&gl[g];
        }
    } else {
        const float* gf = (const float*)Phi;
#pragma unroll
        for (int i = 0; i < 2; i++) {
            int c  = tid + i * 256;
            int r  = c >> 2;
            int cc = c & 3;
            long g = (rowBase + r) * (long)ld + k0 + cc * 8;
            float4 x0 = *(const float4*)&gf[g];
            float4 x1 = *(const float4*)&gf[g + 4];
            float xs[8] = {x0.x, x0.y, x0.z, x0.w, x1.x, x1.y, x1.z, x1.w};
            f16x8 h, l;
#pragma unroll
            for (int e = 0; e < 8; e++) {
                f16 hh = (f16)xs[e];
                h[e] = hh;
                l[e] = (f16)(xs[e] - (float)hh);
            }
            *(f16x8*)&Shi[r * LDS_PITCH + cc * 8] = h;
            *(f16x8*)&Slo[r * LDS_PITCH + cc * 8] = l;
        }
    }
}

// C = A * B^T with split operands. A: [M,K], B: [Nc,K] row-major (per plane).
// Tile 128x128, BK=32, 256 threads = 4 waves, each wave 64x64 (4x4 MFMA 16x16x32 tiles).
template<StageMode SA, StageMode SB, EpiMode EP>
__global__ __launch_bounds__(256, 2)
void mfma_gemm(const void* __restrict__ Ahi, const void* __restrict__ Alo,
               const void* __restrict__ Bhi, const void* __restrict__ Blo,
               void* __restrict__ C0, void* __restrict__ C1,
               int M, int Nc, int K, int lda, int ldb, int ldc,
               long batchA, long batchB, long batchC,
               float epiScale, int tsShift)
{
    const int n0 = blockIdx.x * 128;
    const int m0 = blockIdx.y * 128;
    const long z = blockIdx.z;

    const float* Af32 = (const float*)Ahi;  // used in F32SPLIT mode
    const f16 *Ah = (const f16*)Ahi, *Al = (const f16*)Alo;
    const f16 *Bh = (const f16*)Bhi, *Bl = (const f16*)Blo;

    // batch offsets (elements)
    long aOfs = z * batchA, bOfs = z * batchB, cOfs = z * batchC;

    __shared__ __align__(16) f16 As_hi[128 * LDS_PITCH];
    __shared__ __align__(16) f16 As_lo[128 * LDS_PITCH];
    __shared__ __align__(16) f16 Bs_hi[128 * LDS_PITCH];
    __shared__ __align__(16) f16 Bs_lo[128 * LDS_PITCH];

    const int tid  = threadIdx.x;
    const int lane = tid & 63;
    const int wave = tid >> 6;
    const int wr = (wave >> 1) * 64;   // wave row base in tile
    const int wc = (wave & 1) * 64;    // wave col base in tile
    const int fm = lane & 15;          // fragment row (m or n)
    const int fk = (lane >> 4) * 8;    // fragment k base

    f32x4 acc[4][4];
#pragma unroll
    for (int i = 0; i < 4; i++)
#pragma unroll
        for (int j = 0; j < 4; j++) acc[i][j] = (f32x4){0.f, 0.f, 0.f, 0.f};

    for (int k0 = 0; k0 < K; k0 += 32) {
        if constexpr (SA == STAGE_F32SPLIT)
            stage_tile<SA>(Af32 + aOfs, nullptr, As_hi, As_lo, m0, lda, k0, tid);
        else
            stage_tile<SA>(Ah + aOfs, Al + aOfs, As_hi, As_lo, m0, lda, k0, tid);
        if constexpr (SB == STAGE_F32SPLIT)
            stage_tile<SB>((const float*)Bhi + bOfs, nullptr, Bs_hi, Bs_lo, n0, ldb, k0, tid);
        else
            stage_tile<SB>(Bh + bOfs, Bl + bOfs, Bs_hi, Bs_lo, n0, ldb, k0, tid);
        __syncthreads();

        f16x8 ah[4], al[4], bh[4], bl[4];
#pragma unroll
        for (int i = 0; i < 4; i++) {
            int ro = (wr + i * 16 + fm) * LDS_PITCH + fk;
            int co = (wc + i * 16 + fm) * LDS_PITCH + fk;
            ah[i] = *(const f16x8*)&As_hi[ro];
            al[i] = *(const f16x8*)&As_lo[ro];
            bh[i] = *(const f16x8*)&Bs_hi[co];
            bl[i] = *(const f16x8*)&Bs_lo[co];
        }
#pragma unroll
        for (int i = 0; i < 4; i++) {
#pragma unroll
            for (int j = 0; j < 4; j++) {
                acc[i][j] = __builtin_amdgcn_mfma_f32_16x16x32_f16(ah[i], bh[j], acc[i][j], 0, 0, 0);
                acc[i][j] = __builtin_amdgcn_mfma_f32_16x16x32_f16(ah[i], bl[j], acc[i][j], 0, 0, 0);
                acc[i][j] = __builtin_amdgcn_mfma_f32_16x16x32_f16(al[i], bh[j], acc[i][j], 0, 0, 0);
            }
        }
        __syncthreads();
    }

    // Epilogue. C/D frag: col = lane&15, row = (lane>>4)*4 + reg  [m89-verified]
    const int cr = (lane >> 4) * 4;
    const int cn = lane & 15;
#pragma unroll
    for (int i = 0; i < 4; i++) {
#pragma unroll
        for (int j = 0; j < 4; j++) {
#pragma unroll
            for (int r = 0; r < 4; r++) {
                long mg = m0 + wr + i * 16 + cr + r;
                long ng = n0 + wc + j * 16 + cn;
                float val = acc[i][j][r] * epiScale;
                if constexpr (EP == EPI_F32) {
                    ((float*)C0)[cOfs + mg * ldc + ng] = val;
                } else if constexpr (EP == EPI_SPLIT) {
                    f16 h = (f16)val;
                    ((f16*)C0)[cOfs + mg * ldc + ng] = h;
                    ((f16*)C1)[cOfs + mg * ldc + ng] = (f16)(val - (float)h);
                } else { // EPI_SPLIT_T: batch folded in M; write [nb][n][s]
                    long TS = 1L << tsShift;
                    long nb = mg >> tsShift;
                    long s  = mg & (TS - 1);
                    long addr = nb * ((long)Nc << tsShift) + ng * TS + s;
                    f16 h = (f16)val;
                    ((f16*)C0)[addr] = h;
                    ((f16*)C1)[addr] = (f16)(val - (float)h);
                }
            }
        }
    }
}

// Column softmax (axis = q) on split score planes; writes split P planes.
// s = (hi+lo)*scoreScale ; P = softmax_col(s) * invD
__global__ __launch_bounds__(256)
void softmax_split_kernel(const f16* __restrict__ Shi, const f16* __restrict__ Slo,
                          f16* __restrict__ Phi, f16* __restrict__ Plo,
                          int S, float scoreScale, float invD)
{
    const int n  = blockIdx.y;
    const int c  = threadIdx.x & 63;
    const int qs = threadIdx.x >> 6;
    const int kk = blockIdx.x * 64 + c;
    const long base = (long)n * S * S;
    const f16* sh = Shi + base;
    const f16* sl = Slo + base;
    f16* ph = Phi + base;
    f16* pl = Plo + base;

    __shared__ float red[4][64];

    float m = -INFINITY;
    for (int q = qs; q < S; q += 4) {
        long idx = (long)q * S + kk;
        float s = ((float)sh[idx] + (float)sl[idx]) * scoreScale;
        m = fmaxf(m, s);
    }
    red[qs][c] = m;
    __syncthreads();
    m = fmaxf(fmaxf(red[0][c], red[1][c]), fmaxf(red[2][c], red[3][c]));
    __syncthreads();

    float sum = 0.f;
    for (int q = qs; q < S; q += 4) {
        long idx = (long)q * S + kk;
        float s = ((float)sh[idx] + (float)sl[idx]) * scoreScale;
        sum += expf(s - m);
    }
    red[qs][c] = sum;
    __syncthreads();
    sum = red[0][c] + red[1][c] + red[2][c] + red[3][c];
    const float r = invD / sum;

    for (int q = qs; q < S; q += 4) {
        long idx = (long)q * S + kk;
        float s = ((float)sh[idx] + (float)sl[idx]) * scoreScale;
        float p = expf(s - m) * r;
        f16 h = (f16)p;
        ph[idx] = h;
        pl[idx] = (f16)(p - (float)h);
    }
}

extern "C" void kernel_launch(void* const* d_in, const int* in_sizes, int n_in,
                              void* d_out, int out_size, void* d_ws, size_t ws_size,
                              hipStream_t stream)
{
    const float* v  = (const float*)d_in[0];
    const float* k  = (const float*)d_in[1];
    const float* q  = (const float*)d_in[2];
    const float* WV = (const float*)d_in[3];
    const float* WQ = (const float*)d_in[4];
    const float* WK = (const float*)d_in[5];
    float* out = (float*)d_out;

    const int N = 4, S = 2048, D = 1024;
    const long NSD = (long)N * S * D;   // 8.39M
    const long NSS = (long)N * S * S;   // 16.78M

    f16* ws = (f16*)d_ws;
    // R1: wq/wk planes, later P planes (2*NSS == 4*NSD)
    f16* wq_hi = ws;
    f16* wq_lo = ws + NSD;
    f16* wk_hi = ws + 2 * NSD;
    f16* wk_lo = ws + 3 * NSD;
    f16* P_hi  = ws;             // alias of R1 (wq/wk dead by then)
    f16* P_lo  = ws + NSS;
    // R2: score planes
    f16* Sc_hi = ws + 4 * NSD;
    f16* Sc_lo = ws + 4 * NSD + NSS;
    // R3: wvT planes [N][D][S]
    f16* wvT_hi = ws + 8 * NSD;
    f16* wvT_lo = ws + 9 * NSD;

    dim3 blk(256);

    // Projections: M = N*S folded, C = X @ W^T
    {
        dim3 g(D / 128, (N * S) / 128, 1);
        mfma_gemm<STAGE_F32SPLIT, STAGE_F32SPLIT, EPI_SPLIT><<<g, blk, 0, stream>>>(
            q, nullptr, WQ, nullptr, wq_hi, wq_lo,
            N * S, D, D, D, D, D, 0, 0, 0, 1.0f, 0);
        mfma_gemm<STAGE_F32SPLIT, STAGE_F32SPLIT, EPI_SPLIT><<<g, blk, 0, stream>>>(
            k, nullptr, WK, nullptr, wk_hi, wk_lo,
            N * S, D, D, D, D, D, 0, 0, 0, 1.0f, 0);
        mfma_gemm<STAGE_F32SPLIT, STAGE_F32SPLIT, EPI_SPLIT_T><<<g, blk, 0, stream>>>(
            v, nullptr, WV, nullptr, wvT_hi, wvT_lo,
            N * S, D, D, D, D, 0, 0, 0, 0, 1.0f, 11 /* tsShift: S=2048 */);
    }
    // Scores: Sc[n] = wq[n] @ wk[n]^T, stored as split of (score/16)
    {
        dim3 g(S / 128, S / 128, N);
        mfma_gemm<STAGE_PLANES, STAGE_PLANES, EPI_SPLIT><<<g, blk, 0, stream>>>(
            wq_hi, wq_lo, wk_hi, wk_lo, Sc_hi, Sc_lo,
            S, S, D, D, D, S, (long)S * D, (long)S * D, (long)S * S, 0.0625f, 0);
    }
    // Column softmax (axis=q), /1024, write split P into R1
    {
        dim3 g(S / 64, N);
        softmax_split_kernel<<<g, blk, 0, stream>>>(Sc_hi, Sc_lo, P_hi, P_lo,
                                                    S, 16.0f, 1.0f / (float)D);
    }
    // out[n] = P[n] @ wvT[n]^T  (fp32 out)
    {
        dim3 g(D / 128, S / 128, N);
        mfma_gemm<STAGE_PLANES, STAGE_PLANES, EPI_F32><<<g, blk, 0, stream>>>(
            P_hi, P_lo, wvT_hi, wvT_lo, out, nullptr,
            S, D, S, S, S, D, (long)S * S, (long)S * D, (long)S * D, 1.0f, 0);
    }
}

// Round 3
// 590.854 us; speedup vs baseline: 5.1612x; 1.5341x over previous
//
#include <hip/hip_runtime.h>
#include <math.h>

// N=4, S=2048, D=1024, fp32 in/out.
// Pipeline (GEMMs = f16 MFMA, 2-way fp16 split, 3 cross-products hh+hl+lh):
//   wq = q@WQt, wk = k@WKt (split planes), wvT = (v@WVt)^T (split planes, transposed)
//   Sc = wq@wkt  (f32)
//   column stats (axis=q): m[k], r[k]=1/sum  (2-phase, partials+stats staged in d_out)
//   P = exp(Sc-m)*r  -> split f16 planes (aliases dead wq/wk region)
//   out = (P @ wvT^T) / 1024   (fp32)
// Workspace (167.8 MB, same as round 2):
//   [0 .. 4*NSD)  f16 : wq_hi|wq_lo|wk_hi|wk_lo ; reused as P_hi|P_lo (2*NSS == 4*NSD)
//   [4*NSD..6*NSD) f16: wvT_hi|wvT_lo
//   [6*NSD ..)    f32 : Sc (NSS floats)

typedef _Float16 f16;
typedef _Float16 f16x8 __attribute__((ext_vector_type(8)));
typedef float f32x4 __attribute__((ext_vector_type(4)));

enum StageMode { STAGE_F32SPLIT, STAGE_PLANES };
enum EpiMode   { EPI_F32, EPI_SPLIT, EPI_SPLIT_T };

// LDS tile: 128 rows x 32 k (f16), row pitch 40 f16 (80 B = 5 x 16B chunks;
// 5 coprime with 8 bank-quads -> conflict-free ds_read_b128 across 16 rows).
#define LDS_PITCH 40

template<StageMode SM>
__device__ __forceinline__ void stage_tile(const void* __restrict__ Phi,
                                           const void* __restrict__ Plo,
                                           f16* __restrict__ Shi, f16* __restrict__ Slo,
                                           long rowBase, int ld, int k0, int tid)
{
    if constexpr (SM == STAGE_PLANES) {
        const f16* gh = (const f16*)Phi;
        const f16* gl = (const f16*)Plo;
#pragma unroll
        for (int i = 0; i < 2; i++) {
            int c  = tid + i * 256;      // 512 chunks of 8 f16
            int r  = c >> 2;             // row 0..127
            int cc = c & 3;              // 16B chunk within row
            long g = (rowBase + r) * (long)ld + k0 + cc * 8;
            *(uint4*)&Shi[r * LDS_PITCH + cc * 8] = *(const uint4*)&gh[g];
            *(uint4*)&Slo[r * LDS_PITCH + cc * 8] = *(const uint4*)&gl[g];
        }
    } else {
        const float* gf = (const float*)Phi;
#pragma unroll
        for (int i = 0; i < 2; i++) {
            int c  = tid + i * 256;
            int r  = c >> 2;
            int cc = c & 3;
            long g = (rowBase + r) * (long)ld + k0 + cc * 8;
            float4 x0 = *(const float4*)&gf[g];
            float4 x1 = *(const float4*)&gf[g + 4];
            float xs[8] = {x0.x, x0.y, x0.z, x0.w, x1.x, x1.y, x1.z, x1.w};
            f16x8 h, l;
#pragma unroll
            for (int e = 0; e < 8; e++) {
                f16 hh = (f16)xs[e];
                h[e] = hh;
                l[e] = (f16)(xs[e] - (float)hh);
            }
            *(f16x8*)&Shi[r * LDS_PITCH + cc * 8] = h;
            *(f16x8*)&Slo[r * LDS_PITCH + cc * 8] = l;
        }
    }
}

// C = A * B^T with split operands. A: [M,K], B: [Nc,K] row-major (per plane).
// Tile 128x128, BK=32, 256 threads = 4 waves, each wave 64x64 (4x4 MFMA 16x16x32 tiles).
template<StageMode SA, StageMode SB, EpiMode EP>
__global__ __launch_bounds__(256, 2)
void mfma_gemm(const void* __restrict__ Ahi, const void* __restrict__ Alo,
               const void* __restrict__ Bhi, const void* __restrict__ Blo,
               void* __restrict__ C0, void* __restrict__ C1,
               int M, int Nc, int K, int lda, int ldb, int ldc,
               long batchA, long batchB, long batchC,
               float epiScale, int tsShift)
{
    const int n0 = blockIdx.x * 128;
    const int m0 = blockIdx.y * 128;
    const long z = blockIdx.z;

    const float* Af32 = (const float*)Ahi;  // used in F32SPLIT mode
    const f16 *Ah = (const f16*)Ahi, *Al = (const f16*)Alo;
    const f16 *Bh = (const f16*)Bhi, *Bl = (const f16*)Blo;

    long aOfs = z * batchA, bOfs = z * batchB, cOfs = z * batchC;

    __shared__ __align__(16) f16 As_hi[128 * LDS_PITCH];
    __shared__ __align__(16) f16 As_lo[128 * LDS_PITCH];
    __shared__ __align__(16) f16 Bs_hi[128 * LDS_PITCH];
    __shared__ __align__(16) f16 Bs_lo[128 * LDS_PITCH];

    const int tid  = threadIdx.x;
    const int lane = tid & 63;
    const int wave = tid >> 6;
    const int wr = (wave >> 1) * 64;   // wave row base in tile
    const int wc = (wave & 1) * 64;    // wave col base in tile
    const int fm = lane & 15;          // fragment row (m or n)
    const int fk = (lane >> 4) * 8;    // fragment k base

    f32x4 acc[4][4];
#pragma unroll
    for (int i = 0; i < 4; i++)
#pragma unroll
        for (int j = 0; j < 4; j++) acc[i][j] = (f32x4){0.f, 0.f, 0.f, 0.f};

    for (int k0 = 0; k0 < K; k0 += 32) {
        if constexpr (SA == STAGE_F32SPLIT)
            stage_tile<SA>(Af32 + aOfs, nullptr, As_hi, As_lo, m0, lda, k0, tid);
        else
            stage_tile<SA>(Ah + aOfs, Al + aOfs, As_hi, As_lo, m0, lda, k0, tid);
        if constexpr (SB == STAGE_F32SPLIT)
            stage_tile<SB>((const float*)Bhi + bOfs, nullptr, Bs_hi, Bs_lo, n0, ldb, k0, tid);
        else
            stage_tile<SB>(Bh + bOfs, Bl + bOfs, Bs_hi, Bs_lo, n0, ldb, k0, tid);
        __syncthreads();

        f16x8 ah[4], al[4], bh[4], bl[4];
#pragma unroll
        for (int i = 0; i < 4; i++) {
            int ro = (wr + i * 16 + fm) * LDS_PITCH + fk;
            int co = (wc + i * 16 + fm) * LDS_PITCH + fk;
            ah[i] = *(const f16x8*)&As_hi[ro];
            al[i] = *(const f16x8*)&As_lo[ro];
            bh[i] = *(const f16x8*)&Bs_hi[co];
            bl[i] = *(const f16x8*)&Bs_lo[co];
        }
#pragma unroll
        for (int i = 0; i < 4; i++) {
#pragma unroll
            for (int j = 0; j < 4; j++) {
                acc[i][j] = __builtin_amdgcn_mfma_f32_16x16x32_f16(ah[i], bh[j], acc[i][j], 0, 0, 0);
                acc[i][j] = __builtin_amdgcn_mfma_f32_16x16x32_f16(ah[i], bl[j], acc[i][j], 0, 0, 0);
                acc[i][j] = __builtin_amdgcn_mfma_f32_16x16x32_f16(al[i], bh[j], acc[i][j], 0, 0, 0);
            }
        }
        __syncthreads();
    }

    // Epilogue. C/D frag: col = lane&15, row = (lane>>4)*4 + reg  [m89-verified]
    const int cr = (lane >> 4) * 4;
    const int cn = lane & 15;
#pragma unroll
    for (int i = 0; i < 4; i++) {
#pragma unroll
        for (int j = 0; j < 4; j++) {
#pragma unroll
            for (int r = 0; r < 4; r++) {
                long mg = m0 + wr + i * 16 + cr + r;
                long ng = n0 + wc + j * 16 + cn;
                float val = acc[i][j][r] * epiScale;
                if constexpr (EP == EPI_F32) {
                    ((float*)C0)[cOfs + mg * ldc + ng] = val;
                } else if constexpr (EP == EPI_SPLIT) {
                    f16 h = (f16)val;
                    ((f16*)C0)[cOfs + mg * ldc + ng] = h;
                    ((f16*)C1)[cOfs + mg * ldc + ng] = (f16)(val - (float)h);
                } else { // EPI_SPLIT_T: batch folded in M; write [nb][n][s]
                    long TS = 1L << tsShift;
                    long nb = mg >> tsShift;
                    long s  = mg & (TS - 1);
                    long addr = nb * ((long)Nc << tsShift) + ng * TS + s;
                    f16 h = (f16)val;
                    ((f16*)C0)[addr] = h;
                    ((f16*)C1)[addr] = (f16)(val - (float)h);
                }
            }
        }
    }
}

// ---- Column-softmax stats (axis = q), well-parallelized ----
// Phase A: per (kblock, q-chunk of 128, n): online (max, expsum) partials.
__global__ __launch_bounds__(256)
void stats_partial_kernel(const float* __restrict__ Sc,
                          float* __restrict__ pm, float* __restrict__ ps, int S)
{
    const int n = blockIdx.z, qc = blockIdx.y;
    const int c = threadIdx.x & 63, qs = threadIdx.x >> 6;
    const int kk = blockIdx.x * 64 + c;
    const float* Sn = Sc + (long)n * S * S;
    float m = -INFINITY, s = 0.f;
    const int q0 = qc * 128;
    for (int q = q0 + qs; q < q0 + 128; q += 4) {
        float x = Sn[(long)q * S + kk];
        float nm = fmaxf(m, x);
        s = s * __expf(m - nm) + __expf(x - nm);
        m = nm;
    }
    __shared__ float rm[4][64], rs[4][64];
    rm[qs][c] = m; rs[qs][c] = s;
    __syncthreads();
    if (qs == 0) {
        float M = fmaxf(fmaxf(rm[0][c], rm[1][c]), fmaxf(rm[2][c], rm[3][c]));
        float Ssum = rs[0][c] * __expf(rm[0][c] - M) + rs[1][c] * __expf(rm[1][c] - M)
                   + rs[2][c] * __expf(rm[2][c] - M) + rs[3][c] * __expf(rm[3][c] - M);
        long o = ((long)n * 16 + qc) * S + kk;
        pm[o] = M; ps[o] = Ssum;
    }
}

// Phase B: fold 16 q-chunk partials -> m[k], r[k] = 1/sum.
__global__ __launch_bounds__(64)
void stats_combine_kernel(const float* __restrict__ pm, const float* __restrict__ ps,
                          float* __restrict__ statM, float* __restrict__ statR, int S)
{
    const int n = blockIdx.y;
    const int kk = blockIdx.x * 64 + threadIdx.x;
    float M = -INFINITY;
#pragma unroll
    for (int i = 0; i < 16; i++)
        M = fmaxf(M, pm[((long)n * 16 + i) * S + kk]);
    float Ssum = 0.f;
#pragma unroll
    for (int i = 0; i < 16; i++)
        Ssum += ps[((long)n * 16 + i) * S + kk] * __expf(pm[((long)n * 16 + i) * S + kk] - M);
    statM[(long)n * S + kk] = M;
    statR[(long)n * S + kk] = 1.0f / Ssum;
}

// P = exp(Sc - m[k]) * r[k], split into f16 hi/lo planes.
__global__ __launch_bounds__(256)
void pmat_kernel(const float* __restrict__ Sc, const float* __restrict__ statM,
                 const float* __restrict__ statR,
                 f16* __restrict__ Phi, f16* __restrict__ Plo, int S)
{
    const int n = blockIdx.z, qc = blockIdx.y;
    const int c = threadIdx.x & 63, qs = threadIdx.x >> 6;
    const int kk = blockIdx.x * 64 + c;
    const float* Sn = Sc + (long)n * S * S;
    f16* ph = Phi + (long)n * S * S;
    f16* pl = Plo + (long)n * S * S;
    const float M = statM[(long)n * S + kk];
    const float R = statR[(long)n * S + kk];
    const int q0 = qc * 128;
    for (int q = q0 + qs; q < q0 + 128; q += 4) {
        long idx = (long)q * S + kk;
        float p = __expf(Sn[idx] - M) * R;
        f16 h = (f16)p;
        ph[idx] = h;
        pl[idx] = (f16)(p - (float)h);
    }
}

extern "C" void kernel_launch(void* const* d_in, const int* in_sizes, int n_in,
                              void* d_out, int out_size, void* d_ws, size_t ws_size,
                              hipStream_t stream)
{
    const float* v  = (const float*)d_in[0];
    const float* k  = (const float*)d_in[1];
    const float* q  = (const float*)d_in[2];
    const float* WV = (const float*)d_in[3];
    const float* WQ = (const float*)d_in[4];
    const float* WK = (const float*)d_in[5];
    float* out = (float*)d_out;

    const int N = 4, S = 2048, D = 1024;
    const long NSD = (long)N * S * D;   // 8.39M
    const long NSS = (long)N * S * S;   // 16.78M

    f16* ws = (f16*)d_ws;
    f16* wq_hi = ws;
    f16* wq_lo = ws + NSD;
    f16* wk_hi = ws + 2 * NSD;
    f16* wk_lo = ws + 3 * NSD;
    f16* P_hi  = ws;             // alias of wq/wk region (dead after scores GEMM)
    f16* P_lo  = ws + NSS;
    f16* wvT_hi = ws + 4 * NSD;  // [N][D][S]
    f16* wvT_lo = ws + 5 * NSD;
    float* Sc   = (float*)(ws + 6 * NSD);   // NSS floats

    // Stats scratch lives in d_out (overwritten entirely by the final GEMM;
    // nothing after stats_combine/pmat reads d_out before that write).
    float* pm    = (float*)d_out;            // [N][16][S]
    float* ps    = pm + (long)N * 16 * S;    // [N][16][S]
    float* statM = ps + (long)N * 16 * S;    // [N][S]
    float* statR = statM + (long)N * S;      // [N][S]

    dim3 blk(256);

    // Projections: M = N*S folded, C = X @ W^T
    {
        dim3 g(D / 128, (N * S) / 128, 1);
        mfma_gemm<STAGE_F32SPLIT, STAGE_F32SPLIT, EPI_SPLIT><<<g, blk, 0, stream>>>(
            q, nullptr, WQ, nullptr, wq_hi, wq_lo,
            N * S, D, D, D, D, D, 0, 0, 0, 1.0f, 0);
        mfma_gemm<STAGE_F32SPLIT, STAGE_F32SPLIT, EPI_SPLIT><<<g, blk, 0, stream>>>(
            k, nullptr, WK, nullptr, wk_hi, wk_lo,
            N * S, D, D, D, D, D, 0, 0, 0, 1.0f, 0);
        mfma_gemm<STAGE_F32SPLIT, STAGE_F32SPLIT, EPI_SPLIT_T><<<g, blk, 0, stream>>>(
            v, nullptr, WV, nullptr, wvT_hi, wvT_lo,
            N * S, D, D, D, D, 0, 0, 0, 0, 1.0f, 11 /* tsShift: S=2048 */);
    }
    // Scores: Sc[n] = wq[n] @ wk[n]^T   (f32 out)
    {
        dim3 g(S / 128, S / 128, N);
        mfma_gemm<STAGE_PLANES, STAGE_PLANES, EPI_F32><<<g, blk, 0, stream>>>(
            wq_hi, wq_lo, wk_hi, wk_lo, Sc, nullptr,
            S, S, D, D, D, S, (long)S * D, (long)S * D, (long)S * S, 1.0f, 0);
    }
    // Column stats (axis=q)
    {
        dim3 gA(S / 64, S / 128, N);
        stats_partial_kernel<<<gA, blk, 0, stream>>>(Sc, pm, ps, S);
        dim3 gB(S / 64, N);
        stats_combine_kernel<<<gB, dim3(64), 0, stream>>>(pm, ps, statM, statR, S);
    }
    // P = exp(Sc - m) * r, split planes (into dead wq/wk region)
    {
        dim3 g(S / 64, S / 128, N);
        pmat_kernel<<<g, blk, 0, stream>>>(Sc, statM, statR, P_hi, P_lo, S);
    }
    // out[n] = (P[n] @ wvT[n]^T) / 1024   (fp32 out)
    {
        dim3 g(D / 128, S / 128, N);
        mfma_gemm<STAGE_PLANES, STAGE_PLANES, EPI_F32><<<g, blk, 0, stream>>>(
            P_hi, P_lo, wvT_hi, wvT_lo, out, nullptr,
            S, D, S, S, S, D, (long)S * S, (long)S * D, (long)S * D, 1.0f / (float)D, 0);
    }
}

// Round 4
// 493.775 us; speedup vs baseline: 6.1759x; 1.1966x over previous
//
#include <hip/hip_runtime.h>
#include <math.h>

// N=4, S=2048, D=1024, fp32 in/out.
// Pipeline:
//   wq = q@WQt, wk = k@WKt : f16-split MFMA GEMM, 3 products (hh+hl+lh), split-plane out
//   wvT = (v@WVt)^T        : 1-product (hh) GEMM, f16 hi-only transposed out
//   Sc = wq@wkt            : 3-product GEMM, f32 out
//   column stats (axis=q)  : m[k], r[k]=1/sum  (2-phase partials)
//   out = (P @ wvT^T)/1024 : 1-product GEMM; A-staging computes P = exp(Sc-m)*r on the fly
// Workspace (167.8 MB = 10*NSD f16 units):
//   [0..4*NSD)   f16: wq_hi|wq_lo|wk_hi|wk_lo
//   [4*NSD..5*NSD) f16: wvT_hi  [N][D][S]
//   [5*NSD..9*NSD) f32: Sc (NSS floats)
//   [9*NSD..)    f32: pm|ps|statM|statR (stats scratch, ~0.56 MB)

typedef _Float16 f16;
typedef _Float16 f16x8 __attribute__((ext_vector_type(8)));
typedef float f32x4 __attribute__((ext_vector_type(4)));

enum StageMode { SM_F32SPLIT, SM_F32HI, SM_PLANES2, SM_PLANES1, SM_EXP };
enum EpiMode   { EPI_F32, EPI_SPLIT, EPI_F16T };

// LDS tile: 128 rows x 32 k (f16), row pitch 40 f16 (80 B = 5 x 16B chunks;
// 5 coprime with 8 bank-quads -> conflict-free ds_read_b128 across 16 rows).
#define LDS_PITCH 40

template<StageMode SM>
__device__ __forceinline__ void stage_tile(const void* __restrict__ P0,
                                           const void* __restrict__ P1,
                                           const float* __restrict__ pM,
                                           const float* __restrict__ pR,
                                           f16* __restrict__ Shi, f16* __restrict__ Slo,
                                           long rowBase, int ld, int k0, int tid)
{
    if constexpr (SM == SM_PLANES2 || SM == SM_PLANES1) {
        const f16* gh = (const f16*)P0;
        const f16* gl = (const f16*)P1;
#pragma unroll
        for (int i = 0; i < 2; i++) {
            int c  = tid + i * 256;      // 512 chunks of 8 f16
            int r  = c >> 2;             // row 0..127
            int cc = c & 3;              // 16B chunk within row
            long g = (rowBase + r) * (long)ld + k0 + cc * 8;
            *(uint4*)&Shi[r * LDS_PITCH + cc * 8] = *(const uint4*)&gh[g];
            if constexpr (SM == SM_PLANES2)
                *(uint4*)&Slo[r * LDS_PITCH + cc * 8] = *(const uint4*)&gl[g];
        }
    } else {
        const float* gf = (const float*)P0;
#pragma unroll
        for (int i = 0; i < 2; i++) {
            int c  = tid + i * 256;
            int r  = c >> 2;
            int cc = c & 3;
            long g = (rowBase + r) * (long)ld + k0 + cc * 8;
            float4 x0 = *(const float4*)&gf[g];
            float4 x1 = *(const float4*)&gf[g + 4];
            float xs[8] = {x0.x, x0.y, x0.z, x0.w, x1.x, x1.y, x1.z, x1.w};
            if constexpr (SM == SM_EXP) {
                // P = exp(Sc - M[k]) * R[k]; stats indexed by the k (column) coord
                float4 ma = *(const float4*)&pM[k0 + cc * 8];
                float4 mb = *(const float4*)&pM[k0 + cc * 8 + 4];
                float4 ra = *(const float4*)&pR[k0 + cc * 8];
                float4 rb = *(const float4*)&pR[k0 + cc * 8 + 4];
                float ms[8] = {ma.x, ma.y, ma.z, ma.w, mb.x, mb.y, mb.z, mb.w};
                float rs[8] = {ra.x, ra.y, ra.z, ra.w, rb.x, rb.y, rb.z, rb.w};
                f16x8 h;
#pragma unroll
                for (int e = 0; e < 8; e++)
                    h[e] = (f16)(__expf(xs[e] - ms[e]) * rs[e]);
                *(f16x8*)&Shi[r * LDS_PITCH + cc * 8] = h;
            } else if constexpr (SM == SM_F32HI) {
                f16x8 h;
#pragma unroll
                for (int e = 0; e < 8; e++) h[e] = (f16)xs[e];
                *(f16x8*)&Shi[r * LDS_PITCH + cc * 8] = h;
            } else { // SM_F32SPLIT
                f16x8 h, l;
#pragma unroll
                for (int e = 0; e < 8; e++) {
                    f16 hh = (f16)xs[e];
                    h[e] = hh;
                    l[e] = (f16)(xs[e] - (float)hh);
                }
                *(f16x8*)&Shi[r * LDS_PITCH + cc * 8] = h;
                *(f16x8*)&Slo[r * LDS_PITCH + cc * 8] = l;
            }
        }
    }
}

// C = A * B^T. A: [M,K], B: [Nc,K] row-major (per batch plane).
// Tile 128x128, BK=32, 256 threads = 4 waves, each wave 64x64 (4x4 of 16x16x32).
// TRIPLE (split) mode: 3 MFMA products hh+hl+lh; else 1 (hh).
template<StageMode SA, StageMode SB, EpiMode EP>
__global__ __launch_bounds__(256, 2)
void mfma_gemm(const void* __restrict__ Ahi, const void* __restrict__ Alo,
               const void* __restrict__ Bhi, const void* __restrict__ Blo,
               const float* __restrict__ statM, const float* __restrict__ statR,
               void* __restrict__ C0, void* __restrict__ C1,
               int M, int Nc, int K, int lda, int ldb, int ldc,
               long batchA, long batchB, long batchC,
               float epiScale, int tsShift)
{
    constexpr bool TRIPLE = (SA == SM_F32SPLIT || SA == SM_PLANES2);

    // GROUP_M=4 swizzle for L2 B-panel reuse (all our grids have gridDim.y % 4 == 0)
    int bx, by;
    {
        const int GM = 4;
        int gx = gridDim.x;
        int lin = blockIdx.y * gx + blockIdx.x;
        int nig = GM * gx;
        int gid = lin / nig;
        int rem = lin - gid * nig;
        by = gid * GM + (rem % GM);
        bx = rem / GM;
    }
    const int n0 = bx * 128;
    const int m0 = by * 128;
    const long z = blockIdx.z;

    long aOfs = z * batchA, bOfs = z * batchB, cOfs = z * batchC;
    const float* pM = statM + z * (long)K;   // used only in SM_EXP (K = stat length)
    const float* pR = statR + z * (long)K;

    __shared__ __align__(16) f16 As_hi[128 * LDS_PITCH];
    __shared__ __align__(16) f16 Bs_hi[128 * LDS_PITCH];
    __shared__ __align__(16) f16 As_lo[TRIPLE ? 128 * LDS_PITCH : 8];
    __shared__ __align__(16) f16 Bs_lo[TRIPLE ? 128 * LDS_PITCH : 8];

    const int tid  = threadIdx.x;
    const int lane = tid & 63;
    const int wave = tid >> 6;
    const int wr = (wave >> 1) * 64;
    const int wc = (wave & 1) * 64;
    const int fm = lane & 15;
    const int fk = (lane >> 4) * 8;

    f32x4 acc[4][4];
#pragma unroll
    for (int i = 0; i < 4; i++)
#pragma unroll
        for (int j = 0; j < 4; j++) acc[i][j] = (f32x4){0.f, 0.f, 0.f, 0.f};

    for (int k0 = 0; k0 < K; k0 += 32) {
        {
            const void* a0 = (SA == SM_F32SPLIT || SA == SM_F32HI || SA == SM_EXP)
                           ? (const void*)((const float*)Ahi + aOfs)
                           : (const void*)((const f16*)Ahi + aOfs);
            const void* a1 = (SA == SM_PLANES2) ? (const void*)((const f16*)Alo + aOfs) : nullptr;
            stage_tile<SA>(a0, a1, pM, pR, As_hi, As_lo, m0, lda, k0, tid);
        }
        {
            const void* b0 = (SB == SM_F32SPLIT || SB == SM_F32HI)
                           ? (const void*)((const float*)Bhi + bOfs)
                           : (const void*)((const f16*)Bhi + bOfs);
            const void* b1 = (SB == SM_PLANES2) ? (const void*)((const f16*)Blo + bOfs) : nullptr;
            stage_tile<SB>(b0, b1, nullptr, nullptr, Bs_hi, Bs_lo, n0, ldb, k0, tid);
        }
        __syncthreads();

        f16x8 ah[4], bh[4], al[4], bl[4];
#pragma unroll
        for (int i = 0; i < 4; i++) {
            int ro = (wr + i * 16 + fm) * LDS_PITCH + fk;
            int co = (wc + i * 16 + fm) * LDS_PITCH + fk;
            ah[i] = *(const f16x8*)&As_hi[ro];
            bh[i] = *(const f16x8*)&Bs_hi[co];
            if constexpr (TRIPLE) {
                al[i] = *(const f16x8*)&As_lo[ro];
                bl[i] = *(const f16x8*)&Bs_lo[co];
            }
        }
#pragma unroll
        for (int i = 0; i < 4; i++) {
#pragma unroll
            for (int j = 0; j < 4; j++) {
                acc[i][j] = __builtin_amdgcn_mfma_f32_16x16x32_f16(ah[i], bh[j], acc[i][j], 0, 0, 0);
                if constexpr (TRIPLE) {
                    acc[i][j] = __builtin_amdgcn_mfma_f32_16x16x32_f16(ah[i], bl[j], acc[i][j], 0, 0, 0);
                    acc[i][j] = __builtin_amdgcn_mfma_f32_16x16x32_f16(al[i], bh[j], acc[i][j], 0, 0, 0);
                }
            }
        }
        __syncthreads();
    }

    // Epilogue. C/D frag: col = lane&15, row = (lane>>4)*4 + reg  [m89-verified]
    const int cr = (lane >> 4) * 4;
    const int cn = lane & 15;
#pragma unroll
    for (int i = 0; i < 4; i++) {
#pragma unroll
        for (int j = 0; j < 4; j++) {
#pragma unroll
            for (int r = 0; r < 4; r++) {
                long mg = m0 + wr + i * 16 + cr + r;
                long ng = n0 + wc + j * 16 + cn;
                float val = acc[i][j][r] * epiScale;
                if constexpr (EP == EPI_F32) {
                    ((float*)C0)[cOfs + mg * ldc + ng] = val;
                } else if constexpr (EP == EPI_SPLIT) {
                    f16 h = (f16)val;
                    ((f16*)C0)[cOfs + mg * ldc + ng] = h;
                    ((f16*)C1)[cOfs + mg * ldc + ng] = (f16)(val - (float)h);
                } else { // EPI_F16T: batch folded in M; write [nb][n][s], hi only
                    long TS = 1L << tsShift;
                    long nb = mg >> tsShift;
                    long s  = mg & (TS - 1);
                    long addr = nb * ((long)Nc << tsShift) + ng * TS + s;
                    ((f16*)C0)[addr] = (f16)val;
                }
            }
        }
    }
}

// ---- Column-softmax stats (axis = q) ----
// Phase A: per (kblock, q-chunk of 128, n): online (max, expsum) partials.
__global__ __launch_bounds__(256)
void stats_partial_kernel(const float* __restrict__ Sc,
                          float* __restrict__ pm, float* __restrict__ ps, int S)
{
    const int n = blockIdx.z, qc = blockIdx.y;
    const int c = threadIdx.x & 63, qs = threadIdx.x >> 6;
    const int kk = blockIdx.x * 64 + c;
    const float* Sn = Sc + (long)n * S * S;
    float m = -INFINITY, s = 0.f;
    const int q0 = qc * 128;
    for (int q = q0 + qs; q < q0 + 128; q += 4) {
        float x = Sn[(long)q * S + kk];
        float nm = fmaxf(m, x);
        s = s * __expf(m - nm) + __expf(x - nm);
        m = nm;
    }
    __shared__ float rm[4][64], rs[4][64];
    rm[qs][c] = m; rs[qs][c] = s;
    __syncthreads();
    if (qs == 0) {
        float M = fmaxf(fmaxf(rm[0][c], rm[1][c]), fmaxf(rm[2][c], rm[3][c]));
        float Ssum = rs[0][c] * __expf(rm[0][c] - M) + rs[1][c] * __expf(rm[1][c] - M)
                   + rs[2][c] * __expf(rm[2][c] - M) + rs[3][c] * __expf(rm[3][c] - M);
        long o = ((long)n * 16 + qc) * S + kk;
        pm[o] = M; ps[o] = Ssum;
    }
}

// Phase B: fold 16 q-chunk partials -> m[k], r[k] = 1/sum.
__global__ __launch_bounds__(64)
void stats_combine_kernel(const float* __restrict__ pm, const float* __restrict__ ps,
                          float* __restrict__ statM, float* __restrict__ statR, int S)
{
    const int n = blockIdx.y;
    const int kk = blockIdx.x * 64 + threadIdx.x;
    float M = -INFINITY;
#pragma unroll
    for (int i = 0; i < 16; i++)
        M = fmaxf(M, pm[((long)n * 16 + i) * S + kk]);
    float Ssum = 0.f;
#pragma unroll
    for (int i = 0; i < 16; i++)
        Ssum += ps[((long)n * 16 + i) * S + kk] * __expf(pm[((long)n * 16 + i) * S + kk] - M);
    statM[(long)n * S + kk] = M;
    statR[(long)n * S + kk] = 1.0f / Ssum;
}

extern "C" void kernel_launch(void* const* d_in, const int* in_sizes, int n_in,
                              void* d_out, int out_size, void* d_ws, size_t ws_size,
                              hipStream_t stream)
{
    const float* v  = (const float*)d_in[0];
    const float* k  = (const float*)d_in[1];
    const float* q  = (const float*)d_in[2];
    const float* WV = (const float*)d_in[3];
    const float* WQ = (const float*)d_in[4];
    const float* WK = (const float*)d_in[5];
    float* out = (float*)d_out;

    const int N = 4, S = 2048, D = 1024;
    const long NSD = (long)N * S * D;   // 8.39M
    const long NSS = (long)N * S * S;   // 16.78M

    f16* ws = (f16*)d_ws;
    f16* wq_hi = ws;
    f16* wq_lo = ws + NSD;
    f16* wk_hi = ws + 2 * NSD;
    f16* wk_lo = ws + 3 * NSD;
    f16* wvT_hi = ws + 4 * NSD;              // [N][D][S]
    float* Sc   = (float*)(ws + 5 * NSD);    // NSS floats = 4*NSD f16 units
    float* pm    = (float*)(ws + 9 * NSD);   // [N][16][S]
    float* ps    = pm + (long)N * 16 * S;    // [N][16][S]
    float* statM = ps + (long)N * 16 * S;    // [N][S]
    float* statR = statM + (long)N * S;      // [N][S]

    dim3 blk(256);

    // Projections: M = N*S folded, C = X @ W^T
    {
        dim3 g(D / 128, (N * S) / 128, 1);
        mfma_gemm<SM_F32SPLIT, SM_F32SPLIT, EPI_SPLIT><<<g, blk, 0, stream>>>(
            q, nullptr, WQ, nullptr, nullptr, nullptr, wq_hi, wq_lo,
            N * S, D, D, D, D, D, 0, 0, 0, 1.0f, 0);
        mfma_gemm<SM_F32SPLIT, SM_F32SPLIT, EPI_SPLIT><<<g, blk, 0, stream>>>(
            k, nullptr, WK, nullptr, nullptr, nullptr, wk_hi, wk_lo,
            N * S, D, D, D, D, D, 0, 0, 0, 1.0f, 0);
        // v projection: 1-product, hi-only transposed out [N][D][S]
        mfma_gemm<SM_F32HI, SM_F32HI, EPI_F16T><<<g, blk, 0, stream>>>(
            v, nullptr, WV, nullptr, nullptr, nullptr, wvT_hi, nullptr,
            N * S, D, D, D, D, 0, 0, 0, 0, 1.0f, 11 /* tsShift: S=2048 */);
    }
    // Scores: Sc[n] = wq[n] @ wk[n]^T   (f32 out)
    {
        dim3 g(S / 128, S / 128, N);
        mfma_gemm<SM_PLANES2, SM_PLANES2, EPI_F32><<<g, blk, 0, stream>>>(
            wq_hi, wq_lo, wk_hi, wk_lo, nullptr, nullptr, Sc, nullptr,
            S, S, D, D, D, S, (long)S * D, (long)S * D, (long)S * S, 1.0f, 0);
    }
    // Column stats (axis=q)
    {
        dim3 gA(S / 64, S / 128, N);
        stats_partial_kernel<<<gA, blk, 0, stream>>>(Sc, pm, ps, S);
        dim3 gB(S / 64, N);
        stats_combine_kernel<<<gB, dim3(64), 0, stream>>>(pm, ps, statM, statR, S);
    }
    // out[n] = (P[n] @ wvT[n]^T) / 1024 ; P computed in A-staging from Sc + stats
    {
        dim3 g(D / 128, S / 128, N);
        mfma_gemm<SM_EXP, SM_PLANES1, EPI_F32><<<g, blk, 0, stream>>>(
            Sc, nullptr, wvT_hi, nullptr, statM, statR, out, nullptr,
            S, D, S, S, S, D, (long)S * S, (long)S * D, (long)S * D, 1.0f / (float)D, 0);
    }
}